// Round 2
// baseline (671.540 us; speedup 1.0000x reference)
//
#include <hip/hip_runtime.h>
#include <hip/hip_bf16.h>
#include <math.h>

// FFTMLP: N=32768, T=2048, NF=1025, HIDDEN=128
// Math: rfft(x1)-rfft(x2) = rfft(d), d=x1-x2 (linearity). feats@W1.T folds into
//   At[t][k] = sum_f W1r[k,f]*cos(2pi f t/T) - W1i[k,f]*sin(2pi f t/T)
//   h = relu(d @ At + b1);  out = h . mean_t(W2) + mean(b2)   (mean kills the [N,T] matrix)
#define T_LEN   2048
#define NFREQ   1025
#define HID     128
#define NSAMP   32768
#define NIT     64              // 2048 / 32 t-tiles

typedef __attribute__((ext_vector_type(8)))  short short8v;   // 8 bf16 = 4 VGPR (MFMA A/B frag)
typedef __attribute__((ext_vector_type(16))) float f32x16;    // MFMA C/D frag

// ws layout (bytes):
//   Akg   [64 tiles][16384 B]  @ 0        (1 MB)  pre-tiled+swizzled bf16 hi/lo image of At
//   w2bar [128] f32            @ 1<<20
//   b2bar [1]   f32            @ (1<<20)+512
//   pw    [16][128] f32        @ (1<<20)+1024
//   pb    [16] f32             @ (1<<20)+1024+8192
#define AKG_OFF    0
#define W2BAR_OFF  (1u<<20)
#define B2BAR_OFF  ((1u<<20)+512)
#define PW_OFF     ((1u<<20)+1024)
#define PB_OFF     ((1u<<20)+1024+8192)

// ---------------- K1: partial column-sums of W2, partial sum of b2 ----------------
__global__ __launch_bounds__(128) void k_w2_partial(const float* __restrict__ W2,
                                                    const float* __restrict__ b2,
                                                    float* __restrict__ pw,
                                                    float* __restrict__ pb) {
    const int b = blockIdx.x;      // 16 blocks x 128 t's
    const int c = threadIdx.x;
    const int t0 = b * 128;
    float s0 = 0.f, s1 = 0.f, s2 = 0.f, s3 = 0.f;
    #pragma unroll 4
    for (int i = 0; i < 128; i += 4) {
        s0 += W2[(long)(t0 + i + 0) * HID + c];
        s1 += W2[(long)(t0 + i + 1) * HID + c];
        s2 += W2[(long)(t0 + i + 2) * HID + c];
        s3 += W2[(long)(t0 + i + 3) * HID + c];
    }
    pw[b * HID + c] = (s0 + s1) + (s2 + s3);
    float v = b2[t0 + c];
    for (int o = 32; o > 0; o >>= 1) v += __shfl_down(v, o);
    __shared__ float sred[2];
    if ((threadIdx.x & 63) == 0) sred[threadIdx.x >> 6] = v;
    __syncthreads();
    if (threadIdx.x == 0) pb[b] = sred[0] + sred[1];
}

__global__ __launch_bounds__(128) void k_w2_final(const float* __restrict__ pw,
                                                  const float* __restrict__ pb,
                                                  float* __restrict__ w2bar,
                                                  float* __restrict__ b2bar) {
    const int c = threadIdx.x;
    float s = 0.f;
    #pragma unroll
    for (int b = 0; b < 16; ++b) s += pw[b * HID + c];
    w2bar[c] = s * (1.f / (float)T_LEN);
    if (c == 0) {
        float t = 0.f;
        #pragma unroll
        for (int b = 0; b < 16; ++b) t += pb[b];
        *b2bar = t * (1.f / (float)T_LEN);
    }
}

// ---------------- KA: build Akg (At in tiled+swizzled bf16 hi/lo image) ----------------
// One thread per (k,t): recurrence over f with exact integer-phase resync every 128.
// Store layout: tile=t>>5 (16 KB each = 128 hid-rows x 128 B); row k holds 8 x 16B slots;
// logical slot: hi = (t&31)>>3 (0..3), lo = hi|4; physical slot s = logical ^ (k&7).
__global__ __launch_bounds__(64) void k_build_At(const float* __restrict__ W1,
                                                 unsigned short* __restrict__ Akg) {
    const int k  = blockIdx.x >> 5;          // 0..127
    const int tc = blockIdx.x & 31;
    const int t  = tc * 64 + threadIdx.x;    // 0..2047
    const float* __restrict__ Wr = W1 + (long)k * (2 * NFREQ);
    const float* __restrict__ Wi = Wr + NFREQ;
    const float w = -6.283185307179586f / (float)T_LEN;
    float sr, cr;
    sincosf(w * (float)t, &sr, &cr);
    float zr = 1.f, zi = 0.f;
    float acc = 0.f;
    int f = 0;
    for (int blk = 0; blk < 8; ++blk) {
        #pragma unroll 4
        for (int j = 0; j < 128; ++j) {
            acc = fmaf(Wr[f], zr, acc);
            acc = fmaf(Wi[f], zi, acc);
            float nzr = fmaf(zr, cr, -(zi * sr));
            float nzi = fmaf(zr, sr, zi * cr);
            zr = nzr; zi = nzi;
            ++f;
        }
        int ph = (t * f) & (T_LEN - 1);
        sincosf(w * (float)ph, &zi, &zr);
    }
    acc = fmaf(Wr[1024], zr, acc);
    acc = fmaf(Wi[1024], zi, acc);

    __hip_bfloat16 hb = __float2bfloat16(acc);
    float hf = __bfloat162float(hb);
    __hip_bfloat16 lb = __float2bfloat16(acc - hf);
    const int tile = t >> 5, inner = t & 31, islot = inner >> 3, j = t & 7;
    const int shi = islot ^ (k & 7);
    const int slo = (islot ^ 4) ^ (k & 7);
    const long base = (long)tile * 8192 + k * 64 + j;     // ushort units
    Akg[base + shi * 8] = __builtin_bit_cast(unsigned short, hb);
    Akg[base + slo * 8] = __builtin_bit_cast(unsigned short, lb);
}

// ---------------- KG: fused (x1-x2) @ At -> relu -> dot(w2bar) -> out[N] ----------------
// MFMA 32x32x16 bf16, 3-pass hi/lo split. BM=128, BN=128, BK=32.
// 512 threads = 8 waves: wm=w&3 (rows wm*32..+31), wn=w>>2 (cols wn*64..+63 = 2 n-tiles).
// d loaded straight into A-frags from global (no LDS). Ak double-buffered in LDS,
// reg-staged with linear writes (global image is pre-swizzled), one barrier/iter.
__global__ __launch_bounds__(512) void k_gemm(const float* __restrict__ x1,
                                              const float* __restrict__ x2,
                                              const unsigned short* __restrict__ Akg,
                                              const float* __restrict__ b1,
                                              const float* __restrict__ w2bar,
                                              const float* __restrict__ b2bar,
                                              float* __restrict__ out) {
    __shared__ __align__(16) unsigned short ak[2][8192];   // 2 x 16 KB
    __shared__ float osum[128];

    const int tid = threadIdx.x;
    const int l   = tid & 63;
    const int w   = tid >> 6;          // 0..7
    const int wm  = w & 3;
    const int wn  = w >> 2;
    const int g   = l >> 5;            // k-group within frag
    const int m31 = l & 31;
    const long row0 = (long)blockIdx.x * 128;

    // this lane's x row and k-phase base (A-frag k = kc*16 + 8g + [0..7])
    const float* __restrict__ px1 = x1 + (row0 + wm * 32 + m31) * T_LEN + 8 * g;
    const float* __restrict__ px2 = x2 + (row0 + wm * 32 + m31) * T_LEN + 8 * g;
    // Ak stage source: lane reads 2 x 16B per tile (wave w covers bytes w*2048 + i*1024)
    const unsigned short* __restrict__ pak = Akg + w * 1024 + l * 8;   // ushort units

    f32x16 acc[2];
    #pragma unroll
    for (int tj = 0; tj < 2; ++tj)
        #pragma unroll
        for (int q = 0; q < 16; ++q) acc[tj][q] = 0.f;

    float4 xq[8];   // [0..3]=x1 {kc0:q0,q1, kc1:q0,q1}; [4..7]=x2 same
    uint4  akr[2];

    // prolog: loads for it=0
    {
        const float* p1 = px1; const float* p2 = px2;
        xq[0] = *(const float4*)(p1 + 0);  xq[1] = *(const float4*)(p1 + 4);
        xq[2] = *(const float4*)(p1 + 16); xq[3] = *(const float4*)(p1 + 20);
        xq[4] = *(const float4*)(p2 + 0);  xq[5] = *(const float4*)(p2 + 4);
        xq[6] = *(const float4*)(p2 + 16); xq[7] = *(const float4*)(p2 + 20);
        akr[0] = *(const uint4*)(pak + 0);
        akr[1] = *(const uint4*)(pak + 512);
    }

    for (int it = 0; it < NIT; ++it) {
        const int buf = it & 1;
        // stage Ak tile (linear, conflict-free; data pre-swizzled in global image)
        *(uint4*)&ak[buf][w * 1024 + l * 8]       = akr[0];
        *(uint4*)&ak[buf][w * 1024 + 512 + l * 8] = akr[1];

        // convert x -> bf16 hi/lo A-frags
        short8v dh[2], dl[2];
        #pragma unroll
        for (int kc = 0; kc < 2; ++kc) {
            const float4 a0 = xq[2 * kc], a1 = xq[2 * kc + 1];
            const float4 b0 = xq[4 + 2 * kc], b1v = xq[5 + 2 * kc];
            float dv[8] = {a0.x - b0.x, a0.y - b0.y, a0.z - b0.z, a0.w - b0.w,
                           a1.x - b1v.x, a1.y - b1v.y, a1.z - b1v.z, a1.w - b1v.w};
            #pragma unroll
            for (int e = 0; e < 8; ++e) {
                __hip_bfloat16 hb = __float2bfloat16(dv[e]);
                float lo = dv[e] - __bfloat162float(hb);
                dh[kc][e] = __builtin_bit_cast(short, hb);
                dl[kc][e] = __builtin_bit_cast(short, __float2bfloat16(lo));
            }
        }

        // prefetch next tile (streams under compute; drained by next barrier)
        if (it + 1 < NIT) {
            const float* p1 = px1 + (it + 1) * 32;
            const float* p2 = px2 + (it + 1) * 32;
            xq[0] = *(const float4*)(p1 + 0);  xq[1] = *(const float4*)(p1 + 4);
            xq[2] = *(const float4*)(p1 + 16); xq[3] = *(const float4*)(p1 + 20);
            xq[4] = *(const float4*)(p2 + 0);  xq[5] = *(const float4*)(p2 + 4);
            xq[6] = *(const float4*)(p2 + 16); xq[7] = *(const float4*)(p2 + 20);
            const unsigned short* pa = pak + (long)(it + 1) * 8192;
            akr[0] = *(const uint4*)(pa + 0);
            akr[1] = *(const uint4*)(pa + 512);
        }

        __syncthreads();   // staging visible; prev compute done (single barrier/iter)

        #pragma unroll
        for (int kc = 0; kc < 2; ++kc) {
            #pragma unroll
            for (int tj = 0; tj < 2; ++tj) {
                const int r = wn * 64 + tj * 32 + m31;           // local hid row
                const int shi = ((2 * kc + g) ^ (r & 7)) * 8;
                const int slo = shi ^ 32;                        // (^4 slots)*8 ushorts
                const short8v bh = *(const short8v*)&ak[buf][r * 64 + shi];
                const short8v bl = *(const short8v*)&ak[buf][r * 64 + slo];
                acc[tj] = __builtin_amdgcn_mfma_f32_32x32x16_bf16(dh[kc], bh, acc[tj], 0, 0, 0);
                acc[tj] = __builtin_amdgcn_mfma_f32_32x32x16_bf16(dh[kc], bl, acc[tj], 0, 0, 0);
                acc[tj] = __builtin_amdgcn_mfma_f32_32x32x16_bf16(dl[kc], bh, acc[tj], 0, 0, 0);
            }
        }
    }

    // epilogue: relu(acc + b1) . w2bar, reduce over n (in-lane 2 tiles + 32-lane butterfly
    // + cross-wn via LDS). C/D layout: col = l&31, row = (q&3) + 8*(q>>2) + 4*g  [m74/m101]
    float pres[16];
    #pragma unroll
    for (int q = 0; q < 16; ++q) pres[q] = 0.f;
    #pragma unroll
    for (int tj = 0; tj < 2; ++tj) {
        const int n = wn * 64 + tj * 32 + m31;
        const float bb1 = b1[n], wb = w2bar[n];
        #pragma unroll
        for (int q = 0; q < 16; ++q)
            pres[q] += fmaxf(acc[tj][q] + bb1, 0.f) * wb;
    }
    #pragma unroll
    for (int q = 0; q < 16; ++q) {
        float s = pres[q];
        s += __shfl_xor(s, 1); s += __shfl_xor(s, 2); s += __shfl_xor(s, 4);
        s += __shfl_xor(s, 8); s += __shfl_xor(s, 16);
        pres[q] = s;
    }
    __syncthreads();
    if (wn == 0 && m31 == 0) {
        #pragma unroll
        for (int q = 0; q < 16; ++q)
            osum[wm * 32 + (q & 3) + 8 * (q >> 2) + 4 * g] = pres[q];
    }
    __syncthreads();
    if (wn == 1 && m31 == 0) {
        const float bb = *b2bar;
        #pragma unroll
        for (int q = 0; q < 16; ++q) {
            const int m = wm * 32 + (q & 3) + 8 * (q >> 2) + 4 * g;
            out[row0 + m] = pres[q] + osum[m] + bb;
        }
    }
}

extern "C" void kernel_launch(void* const* d_in, const int* in_sizes, int n_in,
                              void* d_out, int out_size, void* d_ws, size_t ws_size,
                              hipStream_t stream) {
    const float* x1 = (const float*)d_in[0];
    const float* x2 = (const float*)d_in[1];
    const float* W1 = (const float*)d_in[2];
    const float* b1 = (const float*)d_in[3];
    const float* W2 = (const float*)d_in[4];
    const float* b2 = (const float*)d_in[5];
    float* out = (float*)d_out;

    char* ws = (char*)d_ws;
    unsigned short* Akg = (unsigned short*)(ws + AKG_OFF);
    float* w2bar = (float*)(ws + W2BAR_OFF);
    float* b2bar = (float*)(ws + B2BAR_OFF);
    float* pw    = (float*)(ws + PW_OFF);
    float* pb    = (float*)(ws + PB_OFF);

    hipLaunchKernelGGL(k_w2_partial, dim3(16), dim3(128), 0, stream, W2, b2, pw, pb);
    hipLaunchKernelGGL(k_w2_final,   dim3(1),  dim3(128), 0, stream, pw, pb, w2bar, b2bar);
    hipLaunchKernelGGL(k_build_At,   dim3(4096), dim3(64), 0, stream, W1, Akg);
    hipLaunchKernelGGL(k_gemm,       dim3(NSAMP / 128), dim3(512), 0, stream,
                       x1, x2, Akg, b1, w2bar, b2bar, out);
}

// Round 9
// 566.826 us; speedup vs baseline: 1.1847x; 1.1847x over previous
//
#include <hip/hip_runtime.h>
#include <hip/hip_bf16.h>
#include <math.h>

// FFTMLP: N=32768, T=2048, NF=1025, HIDDEN=128
// Math: rfft(x1)-rfft(x2) = rfft(d), d=x1-x2. feats@W1.T folds into
//   At[t][k] = sum_f W1r[k,f]*cos(2pi f t/T) - W1i[k,f]*sin(2pi f t/T)
//   h = relu(d @ At + b1);  out = h . mean_t(W2) + mean(b2)
#define T_LEN   2048
#define NFREQ   1025
#define HID     128
#define NSAMP   32768
#define NIT     64              // 2048 / 32 t-tiles

typedef __attribute__((ext_vector_type(8)))  short short8v;   // 8 bf16 (MFMA A/B frag)
typedef __attribute__((ext_vector_type(16))) float f32x16;    // MFMA C/D frag

// ws layout (bytes)
#define AKG_OFF    0
#define W2BAR_OFF  (1u<<20)
#define B2BAR_OFF  ((1u<<20)+512)
#define PW_OFF     ((1u<<20)+1024)
#define PB_OFF     ((1u<<20)+1024+8192)

// ---------------- K1/K2: w2bar = mean_t W2, b2bar = mean b2 ----------------
__global__ __launch_bounds__(128) void k_w2_partial(const float* __restrict__ W2,
                                                    const float* __restrict__ b2,
                                                    float* __restrict__ pw,
                                                    float* __restrict__ pb) {
    const int b = blockIdx.x;
    const int c = threadIdx.x;
    const int t0 = b * 128;
    float s0 = 0.f, s1 = 0.f, s2 = 0.f, s3 = 0.f;
    #pragma unroll 4
    for (int i = 0; i < 128; i += 4) {
        s0 += W2[(long)(t0 + i + 0) * HID + c];
        s1 += W2[(long)(t0 + i + 1) * HID + c];
        s2 += W2[(long)(t0 + i + 2) * HID + c];
        s3 += W2[(long)(t0 + i + 3) * HID + c];
    }
    pw[b * HID + c] = (s0 + s1) + (s2 + s3);
    float v = b2[t0 + c];
    for (int o = 32; o > 0; o >>= 1) v += __shfl_down(v, o);
    __shared__ float sred[2];
    if ((threadIdx.x & 63) == 0) sred[threadIdx.x >> 6] = v;
    __syncthreads();
    if (threadIdx.x == 0) pb[b] = sred[0] + sred[1];
}

__global__ __launch_bounds__(128) void k_w2_final(const float* __restrict__ pw,
                                                  const float* __restrict__ pb,
                                                  float* __restrict__ w2bar,
                                                  float* __restrict__ b2bar) {
    const int c = threadIdx.x;
    float s = 0.f;
    #pragma unroll
    for (int b = 0; b < 16; ++b) s += pw[b * HID + c];
    w2bar[c] = s * (1.f / (float)T_LEN);
    if (c == 0) {
        float t = 0.f;
        #pragma unroll
        for (int b = 0; b < 16; ++b) t += pb[b];
        *b2bar = t * (1.f / (float)T_LEN);
    }
}

// ---------------- KA: build Akg (At, tiled + XOR-swizzled bf16 hi/lo image) ----------------
// 256-thread blocks (4 waves -> 8 waves/SIMD resident; 2048 blocks total). Per block:
// one k-row of W1 preloaded to LDS (hot loop reads are uniform-addr LDS broadcasts, no
// VMEM). f-dim split 2-ways across lane halves (even/odd, step-2 rotation, chain 512);
// exact integer-phase resync every 128 steps; combine via shfl_xor(32).
__global__ __launch_bounds__(256) void k_build_At(const float* __restrict__ W1,
                                                  unsigned short* __restrict__ Akg) {
    __shared__ float lW[2 * NFREQ];          // [0..1024]=Wr, [1025..2049]=Wi
    const int k  = blockIdx.x >> 4;          // 0..127
    const int tg = blockIdx.x & 15;          // 16 groups of 128 t
    const int tid = threadIdx.x;
    const float* __restrict__ Wk = W1 + (long)k * (2 * NFREQ);
    for (int i = tid; i < 2 * NFREQ; i += 256) lW[i] = Wk[i];
    __syncthreads();
    const float* __restrict__ lWr = lW;
    const float* __restrict__ lWi = lW + NFREQ;

    const int chunk = tid >> 6;              // 0..3 (one 32-t chunk per wave)
    const int fh = (tid >> 5) & 1;           // 0: even f, 1: odd f
    const int tl = tid & 31;
    const int t  = tg * 128 + chunk * 32 + tl;

    const float w = -6.283185307179586f / (float)T_LEN;
    float sr, cr;
    { int ph2 = (2 * t) & (T_LEN - 1); sincosf(w * (float)ph2, &sr, &cr); }  // step e^{-2pi i 2t/T}
    float zr, zi;
    { int ph = (t * fh) & (T_LEN - 1); sincosf(w * (float)ph, &zi, &zr); }
    float acc = 0.f;
    int f = fh;
    for (int blk = 0; blk < 4; ++blk) {
        #pragma unroll 4
        for (int j = 0; j < 128; ++j) {
            acc = fmaf(lWr[f], zr, acc);
            acc = fmaf(lWi[f], zi, acc);     // zi = -sin carries the Im sign
            float nzr = fmaf(zr, cr, -(zi * sr));
            float nzi = fmaf(zr, sr, zi * cr);
            zr = nzr; zi = nzi;
            f += 2;
        }
        int ph = (t * f) & (T_LEN - 1);      // exact resync
        sincosf(w * (float)ph, &zi, &zr);
    }
    if (fh == 0) {                           // Nyquist f=1024 (even stream ends there)
        acc = fmaf(lWr[1024], zr, acc);
        acc = fmaf(lWi[1024], zi, acc);
    }
    acc += __shfl_xor(acc, 32);

    if (fh == 0) {
        __hip_bfloat16 hb = __float2bfloat16(acc);
        float hf = __bfloat162float(hb);
        __hip_bfloat16 lb = __float2bfloat16(acc - hf);
        const int tile = t >> 5, islot = (t & 31) >> 3, j = t & 7;
        const int shi = islot ^ (k & 7);
        const int slo = (islot ^ 4) ^ (k & 7);
        const long base = (long)tile * 8192 + k * 64 + j;     // ushort units
        Akg[base + shi * 8] = __builtin_bit_cast(unsigned short, hb);
        Akg[base + slo * 8] = __builtin_bit_cast(unsigned short, lb);
    }
}

// ---------------- KG: fused (x1-x2) @ At -> relu -> dot(w2bar) -> out[N] ----------------
// MFMA 32x32x16 bf16, 3-pass hi/lo split. BM=128, BN=128(=HID), BK=32.
// 512 threads = 8 waves: wm=w&3 (row tile), wn=w>>2 (2 n-tiles of 32 each).
// x staged COALESCED (thread q: contiguous 32B of row q>>2), converted to bf16 hi/lo in
// regs, written to XOR-swizzled LDS tile; Ak reg-staged from pre-swizzled global image.
// Both LDS tiles double-buffered -> single barrier/iter; x+Ak prefetched 1 tile ahead.
__global__ __launch_bounds__(512) void k_gemm(const float* __restrict__ x1,
                                              const float* __restrict__ x2,
                                              const unsigned short* __restrict__ Akg,
                                              const float* __restrict__ b1,
                                              const float* __restrict__ w2bar,
                                              const float* __restrict__ b2bar,
                                              float* __restrict__ out) {
    __shared__ __align__(16) unsigned short ak[2][8192];   // At tile: [hid 128][8 slots][8 bf16]
    __shared__ __align__(16) unsigned short dd[2][8192];   // d tile: [row 128][8 slots][8 bf16]
    __shared__ float osum[128];

    const int tid = threadIdx.x;
    const int l   = tid & 63;
    const int w   = tid >> 6;          // 0..7
    const int wm  = w & 3;
    const int wn  = w >> 2;
    const int g   = l >> 5;
    const int m31 = l & 31;
    const long row0 = (long)blockIdx.x * 128;

    // staging assignment: thread covers row rs, t-quad j4 (8 consecutive t = 32B)
    const int rs = tid >> 2;
    const int j4 = tid & 3;
    const float* __restrict__ px1 = x1 + (row0 + rs) * T_LEN + j4 * 8;
    const float* __restrict__ px2 = x2 + (row0 + rs) * T_LEN + j4 * 8;
    const unsigned short* __restrict__ pak = Akg + tid * 16;   // 32B per thread, coalesced

    const int wr_hi = rs * 64 + ((j4 ^ (rs & 7)) * 8);         // swizzled hi-slot addr (ushorts)
    const int ra  = wm * 32 + m31;                             // A-frag LDS row
    const int rb0 = wn * 64 + m31;                             // B-frag LDS rows
    const int rb1 = wn * 64 + 32 + m31;

    f32x16 acc[2];
    #pragma unroll
    for (int tj = 0; tj < 2; ++tj)
        #pragma unroll
        for (int q = 0; q < 16; ++q) acc[tj][q] = 0.f;

    float4 xa0, xa1, xb0, xb1;
    uint4  akr0, akr1;
    xa0 = *(const float4*)(px1);     xa1 = *(const float4*)(px1 + 4);
    xb0 = *(const float4*)(px2);     xb1 = *(const float4*)(px2 + 4);
    akr0 = *(const uint4*)(pak);     akr1 = *(const uint4*)(pak + 8);

    for (int it = 0; it < NIT; ++it) {
        const int buf = it & 1;
        // convert d -> bf16 hi/lo and stage (writes conflict-free: 8 lanes/bank-group max)
        float dv[8] = {xa0.x - xb0.x, xa0.y - xb0.y, xa0.z - xb0.z, xa0.w - xb0.w,
                       xa1.x - xb1.x, xa1.y - xb1.y, xa1.z - xb1.z, xa1.w - xb1.w};
        short8v dhv, dlv;
        #pragma unroll
        for (int e = 0; e < 8; ++e) {
            __hip_bfloat16 hb = __float2bfloat16(dv[e]);
            float lo = dv[e] - __bfloat162float(hb);
            dhv[e] = __builtin_bit_cast(short, hb);
            dlv[e] = __builtin_bit_cast(short, __float2bfloat16(lo));
        }
        *(short8v*)&dd[buf][wr_hi]      = dhv;
        *(short8v*)&dd[buf][wr_hi ^ 32] = dlv;
        *(uint4*)&ak[buf][tid * 16]     = akr0;
        *(uint4*)&ak[buf][tid * 16 + 8] = akr1;

        // prefetch next tile (coalesced; streams under this iter's compute)
        if (it + 1 < NIT) {
            const float* p1 = px1 + (it + 1) * 32;
            const float* p2 = px2 + (it + 1) * 32;
            xa0 = *(const float4*)(p1);     xa1 = *(const float4*)(p1 + 4);
            xb0 = *(const float4*)(p2);     xb1 = *(const float4*)(p2 + 4);
            const unsigned short* pa = pak + (long)(it + 1) * 8192;
            akr0 = *(const uint4*)(pa);     akr1 = *(const uint4*)(pa + 8);
        }

        __syncthreads();   // staged tile visible; dbuf makes one barrier/iter sufficient

        #pragma unroll
        for (int kc = 0; kc < 2; ++kc) {
            const int sa = ((2 * kc + g) ^ (ra & 7)) * 8;
            const short8v ah = *(const short8v*)&dd[buf][ra * 64 + sa];
            const short8v al = *(const short8v*)&dd[buf][ra * 64 + (sa ^ 32)];
            #pragma unroll
            for (int tj = 0; tj < 2; ++tj) {
                const int r = (tj == 0) ? rb0 : rb1;
                const int sb = ((2 * kc + g) ^ (r & 7)) * 8;
                const short8v bh = *(const short8v*)&ak[buf][r * 64 + sb];
                const short8v bl = *(const short8v*)&ak[buf][r * 64 + (sb ^ 32)];
                acc[tj] = __builtin_amdgcn_mfma_f32_32x32x16_bf16(ah, bh, acc[tj], 0, 0, 0);
                acc[tj] = __builtin_amdgcn_mfma_f32_32x32x16_bf16(ah, bl, acc[tj], 0, 0, 0);
                acc[tj] = __builtin_amdgcn_mfma_f32_32x32x16_bf16(al, bh, acc[tj], 0, 0, 0);
            }
        }
    }

    // epilogue: relu(acc + b1) . w2bar, reduce over n; C/D: col=l&31, row=(q&3)+8*(q>>2)+4*g
    float pres[16];
    #pragma unroll
    for (int q = 0; q < 16; ++q) pres[q] = 0.f;
    #pragma unroll
    for (int tj = 0; tj < 2; ++tj) {
        const int n = wn * 64 + tj * 32 + m31;
        const float bb1 = b1[n], wb = w2bar[n];
        #pragma unroll
        for (int q = 0; q < 16; ++q)
            pres[q] += fmaxf(acc[tj][q] + bb1, 0.f) * wb;
    }
    #pragma unroll
    for (int q = 0; q < 16; ++q) {
        float s = pres[q];
        s += __shfl_xor(s, 1); s += __shfl_xor(s, 2); s += __shfl_xor(s, 4);
        s += __shfl_xor(s, 8); s += __shfl_xor(s, 16);
        pres[q] = s;
    }
    __syncthreads();
    if (wn == 0 && m31 == 0) {
        #pragma unroll
        for (int q = 0; q < 16; ++q)
            osum[wm * 32 + (q & 3) + 8 * (q >> 2) + 4 * g] = pres[q];
    }
    __syncthreads();
    if (wn == 1 && m31 == 0) {
        const float bb = *b2bar;
        #pragma unroll
        for (int q = 0; q < 16; ++q) {
            const int m = wm * 32 + (q & 3) + 8 * (q >> 2) + 4 * g;
            out[row0 + m] = pres[q] + osum[m] + bb;
        }
    }
}

extern "C" void kernel_launch(void* const* d_in, const int* in_sizes, int n_in,
                              void* d_out, int out_size, void* d_ws, size_t ws_size,
                              hipStream_t stream) {
    const float* x1 = (const float*)d_in[0];
    const float* x2 = (const float*)d_in[1];
    const float* W1 = (const float*)d_in[2];
    const float* b1 = (const float*)d_in[3];
    const float* W2 = (const float*)d_in[4];
    const float* b2 = (const float*)d_in[5];
    float* out = (float*)d_out;

    char* ws = (char*)d_ws;
    unsigned short* Akg = (unsigned short*)(ws + AKG_OFF);
    float* w2bar = (float*)(ws + W2BAR_OFF);
    float* b2bar = (float*)(ws + B2BAR_OFF);
    float* pw    = (float*)(ws + PW_OFF);
    float* pb    = (float*)(ws + PB_OFF);

    hipLaunchKernelGGL(k_w2_partial, dim3(16), dim3(128), 0, stream, W2, b2, pw, pb);
    hipLaunchKernelGGL(k_w2_final,   dim3(1),  dim3(128), 0, stream, pw, pb, w2bar, b2bar);
    hipLaunchKernelGGL(k_build_At,   dim3(2048), dim3(256), 0, stream, W1, Akg);
    hipLaunchKernelGGL(k_gemm,       dim3(NSAMP / 128), dim3(512), 0, stream,
                       x1, x2, Akg, b1, w2bar, b2bar, out);
}